// Round 7
// baseline (152.705 us; speedup 1.0000x reference)
//
#include <hip/hip_runtime.h>
#include <stdint.h>
#include <math.h>

#define BH_ 16
#define N_  2048
#define D_  64
#define NEGV (-1e15f)

typedef __attribute__((ext_vector_type(8))) short bf16x8;
typedef __attribute__((ext_vector_type(8))) unsigned short us8;
typedef __attribute__((ext_vector_type(4))) float f32x4;

// ---------------- workspace layout ----------------
#define OFF_MASKU8 0u
#define OFF_MBITS  32768u                // 16*32 u64
#define OFF_EBITS  65536u                // 2*2048*128 u16 = 1 MB
#define OFF_QBF    1114112u              // 4 MB bf16
#define OFF_KBF    5308416u              // 4 MB
#define OFF_VT     9502720u              // 4 MB (transposed [bh][d][n])
#define WS_NEEDED  13697024u

__device__ __forceinline__ unsigned short f2bf(float f) {
    unsigned u = __float_as_uint(f);
    return (unsigned short)((u + 0x7FFFu + ((u >> 16) & 1u)) >> 16);   // RNE
}

// ---- fused prepass: edge pack (blocks 0..2047), q/k/v convert (2048..2559),
//      mask pack+detect (2560..2575)
__global__ __launch_bounds__(256)
void prep_all(const float* __restrict__ q, const float* __restrict__ k,
              const float* __restrict__ v, const void* __restrict__ mraw,
              const int* __restrict__ edge,
              unsigned short* __restrict__ qbf, unsigned short* __restrict__ kbf,
              unsigned short* __restrict__ vT,
              unsigned short* __restrict__ e16, unsigned long long* __restrict__ mbits)
{
    __shared__ unsigned short shbuf[64][72];
    __shared__ int flag;
    const int bid = blockIdx.x;
    const int t   = threadIdx.x;

    if (bid < 2048) {               // ---- edge -> u16 bitmasks (thread-local)
        const int idx = bid * 256 + t;            // 0..524287
        const int4* p = (const int4*)(edge + (size_t)idx * 16);
        unsigned m = 0;
        #pragma unroll
        for (int i = 0; i < 4; ++i) {
            const int4 vv = p[i];
            m |= (vv.x != 0 ? 1u : 0u) << (i * 4 + 0);
            m |= (vv.y != 0 ? 1u : 0u) << (i * 4 + 1);
            m |= (vv.z != 0 ? 1u : 0u) << (i * 4 + 2);
            m |= (vv.w != 0 ? 1u : 0u) << (i * 4 + 3);
        }
        e16[idx] = (unsigned short)m;
    } else if (bid < 2560) {        // ---- q,k -> bf16; v -> bf16 transposed
        const int b2 = bid - 2048;
        const int rt = b2 & 31, bh = b2 >> 5;
        const size_t base = ((size_t)bh * N_ + (size_t)rt * 64) * D_;
        #pragma unroll
        for (int i = 0; i < 4; ++i) {
            const int idx = t + i * 256;
            float4 f = *(const float4*)(q + base + (size_t)idx * 4);
            ushort4 s; s.x = f2bf(f.x); s.y = f2bf(f.y); s.z = f2bf(f.z); s.w = f2bf(f.w);
            *(ushort4*)(qbf + base + (size_t)idx * 4) = s;
            f = *(const float4*)(k + base + (size_t)idx * 4);
            s.x = f2bf(f.x); s.y = f2bf(f.y); s.z = f2bf(f.z); s.w = f2bf(f.w);
            *(ushort4*)(kbf + base + (size_t)idx * 4) = s;
            f = *(const float4*)(v + base + (size_t)idx * 4);
            const int row = idx >> 4;
            const int d0  = (idx & 15) * 4;
            shbuf[d0 + 0][row] = f2bf(f.x);
            shbuf[d0 + 1][row] = f2bf(f.y);
            shbuf[d0 + 2][row] = f2bf(f.z);
            shbuf[d0 + 3][row] = f2bf(f.w);
        }
        __syncthreads();
        const int d  = t >> 2;
        const int c4 = (t & 3) * 16;
        const size_t ob = ((size_t)bh * D_ + d) * N_ + (size_t)rt * 64 + c4;
        *(us8*)(vT + ob)     = *(us8*)&shbuf[d][c4];
        *(us8*)(vT + ob + 8) = *(us8*)&shbuf[d][c4 + 8];
    } else {                        // ---- mask detect + pack
        const int bh = bid - 2560;
        if (t == 0) flag = 0;
        __syncthreads();
        const int* mi = (const int*)mraw;
        int bad = 0;
        for (int i = t; i < 8192; i += 256)
            if ((unsigned)mi[i] > 1u) bad = 1;
        if (bad) atomicOr(&flag, 1);
        __syncthreads();
        const int is_u8 = flag;
        const uint8_t* m8 = (const uint8_t*)mraw;
        const int w4 = t >> 6, l = t & 63;
        for (int it = 0; it < 8; ++it) {
            const int pos = bh * 2048 + it * 256 + w4 * 64 + l;
            const bool on = is_u8 ? (m8[pos] != 0) : (mi[pos] != 0);
            unsigned long long bal = __ballot(on);
            if (l == 0) mbits[bh * 32 + it * 4 + w4] = bal;
        }
    }
}

// ---- main: 4 waves/block, 16 query rows/block.
// Pass 1: wave-private chunk split (kc%4==w), barrier-free, K staged in sKV[w].
// Pass 2: block-cooperative — all waves on chunk kc; wave w owns key subtile
// nt=w for QK^T/attn-store and d-slice w for PV. K/V block-shared double
// buffers + one shared P tile; 2 barriers/chunk. LDS 34.5 KB -> 4 blocks/CU.
__global__ __launch_bounds__(256)
void attn_v4(const unsigned short* __restrict__ qbf,
             const unsigned short* __restrict__ kbf,
             const unsigned short* __restrict__ vT,
             const unsigned long long* __restrict__ ebits,
             const unsigned long long* __restrict__ mbits,
             float* __restrict__ out, float* __restrict__ attn)
{
    __shared__ unsigned short sKV[4][4096];  // pass1: private[w]; pass2: K0,K1,V0,V1
    __shared__ char  pbufS[2048];            // shared 16x64 bf16 P tile (swizzled)
    __shared__ float lsum[4][16];

    const int tile = blockIdx.x;    // 0..127
    const int bh   = blockIdx.y;
    const int t    = threadIdx.x;
    const int w    = t >> 6;
    const int lane = t & 63;
    const int l15  = lane & 15;
    const int lg   = lane >> 4;
    const int l8   = lane & 7;
    const int lrow = lane >> 3;     // 0..7
    const int rbase = tile * 16;

    const unsigned short* qb = qbf + (size_t)bh * N_ * D_;
    const unsigned short* kb = kbf + (size_t)bh * N_ * D_;
    const unsigned short* vb = vT  + (size_t)bh * D_ * N_;
    const unsigned long long* ebrow =
        ebits + ((size_t)(bh & 1) * N_ + (size_t)(rbase + l15)) * 32;
    const unsigned long long* mb = mbits + bh * 32;
    float* outb = out + (size_t)bh * N_ * D_;
    float* arow = attn + (size_t)bh * N_ * N_ + (size_t)(rbase + l15) * N_ + lg * 4;

    // Q fragments (B-operand of swapped QK^T)
    const bf16x8 aq0 = *(const bf16x8*)(qb + (size_t)(rbase + l15) * D_ + lg * 8);
    const bf16x8 aq1 = *(const bf16x8*)(qb + (size_t)(rbase + l15) * D_ + lg * 8 + 32);

    // =============== PASS 1: wave-private, barrier-free (round-6 scheme) ===============
    unsigned short* myk = sKV[w];
    const int sb = lrow * 64 + ((l8 ^ lrow) * 8);   // private-staging slot (swizzled)
    float lacc = 0.f;
    {
        const unsigned short* src = kb + (size_t)w * 4096;
        us8 rk[8];
        #pragma unroll
        for (int j = 0; j < 8; ++j) rk[j] = *(const us8*)(src + j * 512 + lane * 8);
        #pragma unroll
        for (int j = 0; j < 8; ++j) *(us8*)(myk + j * 512 + sb) = rk[j];
    }
    #pragma unroll 1
    for (int i = 0; i < 8; ++i) {
        const int kc = i * 4 + w;
        us8 nk[8];
        if (i < 7) {
            const unsigned short* src = kb + (size_t)(kc + 4) * 4096;
            #pragma unroll
            for (int j = 0; j < 8; ++j) nk[j] = *(const us8*)(src + j * 512 + lane * 8);
        }
        const unsigned long long wbits = ebrow[kc] & ~mb[kc];
        #pragma unroll
        for (int nt = 0; nt < 4; ++nt) {
            const int row = nt * 16 + l15, sw = row & 7;
            const bf16x8 k0 = *(const bf16x8*)(myk + row * 64 + ((lg ^ sw) * 8));
            const bf16x8 k1 = *(const bf16x8*)(myk + row * 64 + (((lg + 4) ^ sw) * 8));
            f32x4 c = (f32x4){0.f, 0.f, 0.f, 0.f};
            c = __builtin_amdgcn_mfma_f32_16x16x32_bf16(k0, aq0, c, 0, 0, 0);
            c = __builtin_amdgcn_mfma_f32_16x16x32_bf16(k1, aq1, c, 0, 0, 0);
            const unsigned bits = (unsigned)(wbits >> (nt * 16 + lg * 4)) & 0xFu;
            #pragma unroll
            for (int r = 0; r < 4; ++r)
                lacc += ((bits >> r) & 1u) ? __expf(c[r] * 0.125f) : 0.f;
        }
        if (i < 7) {
            #pragma unroll
            for (int j = 0; j < 8; ++j) *(us8*)(myk + j * 512 + sb) = nk[j];
        }
    }
    lacc += __shfl_xor(lacc, 16);
    lacc += __shfl_xor(lacc, 32);
    lsum[w][l15] = lacc;
    __syncthreads();
    const float inv = 1.0f / (lsum[0][l15] + lsum[1][l15] + lsum[2][l15] + lsum[3][l15]);

    // =============== PASS 2: cooperative, double-buffered K/V ===============
    // cooperative staging: thread t covers 16B slots s=t and s=t+256 of each 8KB tile
    const int s0row = t >> 3;               // 0..31
    const int s1row = s0row + 32;           // 32..63
    const int t8    = t & 7;
    const int ds0 = s0row * 64 + ((t8 ^ (s0row & 7)) * 8);
    const int ds1 = s1row * 64 + ((t8 ^ (s1row & 7)) * 8);

    {   // prologue: stage K[0] -> sKV[0], V[0] -> sKV[2]
        const us8 a0 = *(const us8*)(kb + (size_t)t * 8);
        const us8 a1 = *(const us8*)(kb + (size_t)(t + 256) * 8);
        const us8 b0 = *(const us8*)(vb + (size_t)s0row * 2048 + t8 * 8);
        const us8 b1 = *(const us8*)(vb + (size_t)s1row * 2048 + t8 * 8);
        *(us8*)(sKV[0] + ds0) = a0;
        *(us8*)(sKV[0] + ds1) = a1;
        *(us8*)(sKV[2] + ds0) = b0;
        *(us8*)(sKV[2] + ds1) = b1;
        __syncthreads();
    }

    f32x4 o = (f32x4){0.f, 0.f, 0.f, 0.f};
    const int swzP = (l15 & 7) << 4;
    const int ab0 = (l15 * 128 + lg * 16)      ^ swzP;
    const int ab1 = (l15 * 128 + lg * 16 + 64) ^ swzP;
    const int pwb = (l15 * 128 + w * 32 + lg * 8) ^ swzP;  // XOR last (round-4 lesson)
    const int rowq = w * 16 + l15;          // K-row (QK^T) and V d-row (PV) for wave w
    const int swq  = l15 & 7;               // rowq & 7 == l15 & 7
    const int koff0 = rowq * 64 + ((lg ^ swq) * 8);
    const int koff1 = rowq * 64 + (((lg + 4) ^ swq) * 8);

    #pragma unroll 1
    for (int kc = 0; kc < 32; ++kc) {
        const int cur = kc & 1;
        us8 nk0, nk1, nv0, nv1;
        if (kc < 31) {   // issue next chunk's loads early (hide under compute)
            const unsigned short* srck = kb + (size_t)(kc + 1) * 4096;
            const unsigned short* srcv = vb + (size_t)(kc + 1) * 64;
            nk0 = *(const us8*)(srck + (size_t)t * 8);
            nk1 = *(const us8*)(srck + (size_t)(t + 256) * 8);
            nv0 = *(const us8*)(srcv + (size_t)s0row * 2048 + t8 * 8);
            nv1 = *(const us8*)(srcv + (size_t)s1row * 2048 + t8 * 8);
        }
        // QK^T for key subtile nt=w
        const unsigned short* kcur = sKV[cur];
        const bf16x8 k0 = *(const bf16x8*)(kcur + koff0);
        const bf16x8 k1 = *(const bf16x8*)(kcur + koff1);
        f32x4 c = (f32x4){0.f, 0.f, 0.f, 0.f};
        c = __builtin_amdgcn_mfma_f32_16x16x32_bf16(k0, aq0, c, 0, 0, 0);
        c = __builtin_amdgcn_mfma_f32_16x16x32_bf16(k1, aq1, c, 0, 0, 0);
        const unsigned long long wbits = ebrow[kc] & ~mb[kc];
        const unsigned bits = (unsigned)(wbits >> (w * 16 + lg * 4)) & 0xFu;
        float4 e;
        e.x = (bits & 1u) ? __expf(c[0] * 0.125f) * inv : 0.f;
        e.y = (bits & 2u) ? __expf(c[1] * 0.125f) * inv : 0.f;
        e.z = (bits & 4u) ? __expf(c[2] * 0.125f) * inv : 0.f;
        e.w = (bits & 8u) ? __expf(c[3] * 0.125f) * inv : 0.f;
        *(float4*)(arow + kc * 64 + w * 16) = e;    // 4 contiguous keys, row l15
        ushort4 pe;
        pe.x = f2bf(e.x); pe.y = f2bf(e.y); pe.z = f2bf(e.z); pe.w = f2bf(e.w);
        *(ushort4*)(pbufS + pwb) = pe;              // P quarter -> shared tile

        __syncthreads();                             // P complete; K[cur] consumed

        // PV: full P rows x V d-slice w
        const bf16x8 ap0 = *(const bf16x8*)(pbufS + ab0);
        const bf16x8 ap1 = *(const bf16x8*)(pbufS + ab1);
        const unsigned short* vcur = sKV[2 + cur];
        const bf16x8 bv0 = *(const bf16x8*)(vcur + koff0);
        const bf16x8 bv1 = *(const bf16x8*)(vcur + koff1);
        o = __builtin_amdgcn_mfma_f32_16x16x32_bf16(ap0, bv0, o, 0, 0, 0);
        o = __builtin_amdgcn_mfma_f32_16x16x32_bf16(ap1, bv1, o, 0, 0, 0);

        if (kc < 31) {   // write next chunk into the other buffer
            unsigned short* kn = sKV[cur ^ 1];
            unsigned short* vn = sKV[2 + (cur ^ 1)];
            *(us8*)(kn + ds0) = nk0;
            *(us8*)(kn + ds1) = nk1;
            *(us8*)(vn + ds0) = nv0;
            *(us8*)(vn + ds1) = nv1;
        }
        __syncthreads();                             // next buffers ready; P reads done
    }

    // out: wave w owns d-slice w completely (no cross-wave reduction needed)
    #pragma unroll
    for (int r = 0; r < 4; ++r)
        outb[(size_t)(rbase + lg * 4 + r) * D_ + w * 16 + l15] = o[r];
}

// ================= fallback (fp32 path, needs only 32 KB ws) =================
__global__ __launch_bounds__(256)
void normalize_mask(const void* __restrict__ mask_raw, uint8_t* __restrict__ mask_out)
{
    __shared__ int is_u8;
    const int t = threadIdx.x;
    if (t == 0) is_u8 = 0;
    __syncthreads();
    const int* mi = (const int*)mask_raw;
    int bad = 0;
    for (int i = t; i < 8192; i += 256)
        if ((unsigned)mi[i] > 1u) bad = 1;
    if (bad) atomicOr(&is_u8, 1);
    __syncthreads();
    const int total = BH_ * N_;
    if (is_u8) {
        const uint8_t* m8 = (const uint8_t*)mask_raw;
        for (int i = t; i < total; i += 256) mask_out[i] = m8[i] ? 1 : 0;
    } else {
        for (int i = t; i < total; i += 256) mask_out[i] = (uint8_t)mi[i];
    }
}

__global__ __launch_bounds__(256)
void attn_fused(const float* __restrict__ q, const float* __restrict__ k,
                const float* __restrict__ v, const uint8_t* __restrict__ mask,
                const int* __restrict__ edge, float* __restrict__ out,
                float* __restrict__ attn)
{
    __shared__ float qsT[D_][64 + 4];
    __shared__ float kt [D_][64 + 4];
    __shared__ float vs [64][D_ + 4];
    const int tile = blockIdx.x, bh = blockIdx.y, t = threadIdx.x;
    const int rg = t >> 4, cg = t & 15, r0 = rg * 4, c0 = cg * 4;
    const int row_base = tile * 64;
    const float* qb = q + (size_t)bh * N_ * D_;
    const float* kb = k + (size_t)bh * N_ * D_;
    const float* vb = v + (size_t)bh * N_ * D_;
    const uint8_t* mbp = mask + (size_t)bh * N_;
    const int* ebp = edge + (size_t)(bh & 1) * N_ * N_;
    float* outb = out + (size_t)bh * N_ * D_;
    float* attnb = attn + (size_t)bh * N_ * N_;
    {
        const int rr = t >> 2, dblk = (t & 3) * 16;
        const float* src = qb + (size_t)(row_base + rr) * D_ + dblk;
        #pragma unroll
        for (int qq = 0; qq < 4; ++qq) {
            float4 val = *(const float4*)(src + qq * 4);
            qsT[dblk + qq*4 + 0][rr] = val.x; qsT[dblk + qq*4 + 1][rr] = val.y;
            qsT[dblk + qq*4 + 2][rr] = val.z; qsT[dblk + qq*4 + 3][rr] = val.w;
        }
    }
    float m_i[4], l_i[4];
    #pragma unroll
    for (int i = 0; i < 4; ++i) { m_i[i] = -INFINITY; l_i[i] = 0.f; }
    for (int kc = 0; kc < 32; ++kc) {
        __syncthreads();
        {
            const int ccr = t >> 2, dblk = (t & 3) * 16;
            const float* src = kb + (size_t)(kc * 64 + ccr) * D_ + dblk;
            #pragma unroll
            for (int qq = 0; qq < 4; ++qq) {
                float4 val = *(const float4*)(src + qq * 4);
                kt[dblk + qq*4 + 0][ccr] = val.x; kt[dblk + qq*4 + 1][ccr] = val.y;
                kt[dblk + qq*4 + 2][ccr] = val.z; kt[dblk + qq*4 + 3][ccr] = val.w;
            }
        }
        __syncthreads();
        float sc[4][4];
        #pragma unroll
        for (int i = 0; i < 4; ++i) { sc[i][0]=sc[i][1]=sc[i][2]=sc[i][3]=0.f; }
        for (int d = 0; d < D_; ++d) {
            const float4 qv = *(const float4*)&qsT[d][r0];
            const float4 kv = *(const float4*)&kt[d][c0];
            #pragma unroll
            for (int i = 0; i < 4; ++i) {
                const float qi = (i==0)?qv.x:(i==1)?qv.y:(i==2)?qv.z:qv.w;
                sc[i][0] = fmaf(qi, kv.x, sc[i][0]); sc[i][1] = fmaf(qi, kv.y, sc[i][1]);
                sc[i][2] = fmaf(qi, kv.z, sc[i][2]); sc[i][3] = fmaf(qi, kv.w, sc[i][3]);
            }
        }
        const int cbase = kc * 64 + c0;
        const uint8_t m0 = mbp[cbase], m1 = mbp[cbase+1], m2 = mbp[cbase+2], m3 = mbp[cbase+3];
        #pragma unroll
        for (int i = 0; i < 4; ++i) {
            const int rglob = row_base + r0 + i;
            const int4 e4 = *(const int4*)(ebp + (size_t)rglob * N_ + cbase);
            float s0 = sc[i][0]*0.125f, s1 = sc[i][1]*0.125f, s2 = sc[i][2]*0.125f, s3 = sc[i][3]*0.125f;
            if (e4.x == 0 || m0) s0 = NEGV; if (e4.y == 0 || m1) s1 = NEGV;
            if (e4.z == 0 || m2) s2 = NEGV; if (e4.w == 0 || m3) s3 = NEGV;
            float cmax = fmaxf(fmaxf(s0,s1), fmaxf(s2,s3));
            cmax = fmaxf(cmax, __shfl_xor(cmax,1)); cmax = fmaxf(cmax, __shfl_xor(cmax,2));
            cmax = fmaxf(cmax, __shfl_xor(cmax,4)); cmax = fmaxf(cmax, __shfl_xor(cmax,8));
            const float nm = fmaxf(m_i[i], cmax);
            float ss = __expf(s0-nm)+__expf(s1-nm)+__expf(s2-nm)+__expf(s3-nm);
            ss += __shfl_xor(ss,1); ss += __shfl_xor(ss,2); ss += __shfl_xor(ss,4); ss += __shfl_xor(ss,8);
            l_i[i] = l_i[i]*__expf(m_i[i]-nm) + ss; m_i[i] = nm;
        }
    }
    float inv_l[4];
    #pragma unroll
    for (int i = 0; i < 4; ++i) inv_l[i] = 1.0f / l_i[i];
    float oacc[4][4];
    #pragma unroll
    for (int i = 0; i < 4; ++i) { oacc[i][0]=oacc[i][1]=oacc[i][2]=oacc[i][3]=0.f; }
    for (int kc = 0; kc < 32; ++kc) {
        __syncthreads();
        {
            const int ccr = t >> 2, dblk = (t & 3) * 16;
            const float* src = kb + (size_t)(kc * 64 + ccr) * D_ + dblk;
            #pragma unroll
            for (int qq = 0; qq < 4; ++qq) {
                float4 val = *(const float4*)(src + qq * 4);
                kt[dblk + qq*4 + 0][ccr] = val.x; kt[dblk + qq*4 + 1][ccr] = val.y;
                kt[dblk + qq*4 + 2][ccr] = val.z; kt[dblk + qq*4 + 3][ccr] = val.w;
            }
            const float* srcv = vb + (size_t)(kc * 64 + ccr) * D_ + dblk;
            #pragma unroll
            for (int qq = 0; qq < 4; ++qq)
                *(float4*)&vs[ccr][dblk + qq * 4] = *(const float4*)(srcv + qq * 4);
        }
        __syncthreads();
        float sc[4][4];
        #pragma unroll
        for (int i = 0; i < 4; ++i) { sc[i][0]=sc[i][1]=sc[i][2]=sc[i][3]=0.f; }
        for (int d = 0; d < D_; ++d) {
            const float4 qv = *(const float4*)&qsT[d][r0];
            const float4 kv = *(const float4*)&kt[d][c0];
            #pragma unroll
            for (int i = 0; i < 4; ++i) {
                const float qi = (i==0)?qv.x:(i==1)?qv.y:(i==2)?qv.z:qv.w;
                sc[i][0] = fmaf(qi, kv.x, sc[i][0]); sc[i][1] = fmaf(qi, kv.y, sc[i][1]);
                sc[i][2] = fmaf(qi, kv.z, sc[i][2]); sc[i][3] = fmaf(qi, kv.w, sc[i][3]);
            }
        }
        const int cbase = kc * 64 + c0;
        const uint8_t m0 = mbp[cbase], m1 = mbp[cbase+1], m2 = mbp[cbase+2], m3 = mbp[cbase+3];
        float p[4][4];
        #pragma unroll
        for (int i = 0; i < 4; ++i) {
            const int rglob = row_base + r0 + i;
            const int4 e4 = *(const int4*)(ebp + (size_t)rglob * N_ + cbase);
            float s0 = sc[i][0]*0.125f, s1 = sc[i][1]*0.125f, s2 = sc[i][2]*0.125f, s3 = sc[i][3]*0.125f;
            if (e4.x == 0 || m0) s0 = NEGV; if (e4.y == 0 || m1) s1 = NEGV;
            if (e4.z == 0 || m2) s2 = NEGV; if (e4.w == 0 || m3) s3 = NEGV;
            p[i][0] = __expf(s0-m_i[i])*inv_l[i]; p[i][1] = __expf(s1-m_i[i])*inv_l[i];
            p[i][2] = __expf(s2-m_i[i])*inv_l[i]; p[i][3] = __expf(s3-m_i[i])*inv_l[i];
            *(float4*)&attnb[(size_t)rglob * N_ + cbase] = make_float4(p[i][0],p[i][1],p[i][2],p[i][3]);
        }
        __syncthreads();
        #pragma unroll
        for (int i = 0; i < 4; ++i)
            *(float4*)&kt[r0 + i][c0] = make_float4(p[i][0],p[i][1],p[i][2],p[i][3]);
        __syncthreads();
        for (int c4 = 0; c4 < 64; c4 += 4) {
            float prr[4][4];
            #pragma unroll
            for (int i = 0; i < 4; ++i) {
                const float4 tmp = *(const float4*)&kt[r0 + i][c4];
                prr[i][0]=tmp.x; prr[i][1]=tmp.y; prr[i][2]=tmp.z; prr[i][3]=tmp.w;
            }
            #pragma unroll
            for (int cc = 0; cc < 4; ++cc) {
                const float4 vv = *(const float4*)&vs[c4 + cc][c0];
                #pragma unroll
                for (int i = 0; i < 4; ++i) {
                    oacc[i][0] = fmaf(prr[i][cc], vv.x, oacc[i][0]);
                    oacc[i][1] = fmaf(prr[i][cc], vv.y, oacc[i][1]);
                    oacc[i][2] = fmaf(prr[i][cc], vv.z, oacc[i][2]);
                    oacc[i][3] = fmaf(prr[i][cc], vv.w, oacc[i][3]);
                }
            }
        }
    }
    #pragma unroll
    for (int i = 0; i < 4; ++i)
        *(float4*)&outb[(size_t)(row_base + r0 + i) * D_ + c0] =
            make_float4(oacc[i][0], oacc[i][1], oacc[i][2], oacc[i][3]);
}

extern "C" void kernel_launch(void* const* d_in, const int* in_sizes, int n_in,
                              void* d_out, int out_size, void* d_ws, size_t ws_size,
                              hipStream_t stream) {
    const float* q    = (const float*)d_in[0];
    const float* k    = (const float*)d_in[1];
    const float* v    = (const float*)d_in[2];
    // d_in[3] = k2 (unused by the reference)
    const void*  mraw = d_in[4];
    const int*   edge = (const int*)d_in[5];

    float* out  = (float*)d_out;                         // [16][2048][64]
    float* attn = (float*)d_out + (size_t)BH_ * N_ * D_; // [16][2048][2048]

    char* ws = (char*)d_ws;

    if (ws_size < (size_t)WS_NEEDED) {
        uint8_t* mask_u8 = (uint8_t*)(ws + OFF_MASKU8);
        normalize_mask<<<1, 256, 0, stream>>>(mraw, mask_u8);
        attn_fused<<<dim3(32, 16), 256, 0, stream>>>(q, k, v, mask_u8, edge, out, attn);
        return;
    }

    unsigned long long* mbits = (unsigned long long*)(ws + OFF_MBITS);
    unsigned short*     e16   = (unsigned short*)(ws + OFF_EBITS);
    unsigned short*     qbf   = (unsigned short*)(ws + OFF_QBF);
    unsigned short*     kbf   = (unsigned short*)(ws + OFF_KBF);
    unsigned short*     vT    = (unsigned short*)(ws + OFF_VT);

    prep_all<<<dim3(2576), 256, 0, stream>>>(q, k, v, mraw, edge,
                                             qbf, kbf, vT, e16, mbits);
    attn_v4<<<dim3(N_ / 16, BH_), 256, 0, stream>>>(
        qbf, kbf, vT, (const unsigned long long*)e16, mbits, out, attn);
}

// Round 8
// 125.953 us; speedup vs baseline: 1.2124x; 1.2124x over previous
//
#include <hip/hip_runtime.h>
#include <stdint.h>
#include <math.h>

#define BH_ 16
#define N_  2048
#define D_  64
#define NEGV (-1e15f)

typedef __attribute__((ext_vector_type(8))) short bf16x8;
typedef __attribute__((ext_vector_type(8))) unsigned short us8;
typedef __attribute__((ext_vector_type(4))) float f32x4;

// ---------------- workspace layout ----------------
#define OFF_MASKU8 0u
#define OFF_MBITS  32768u                // 16*32 u64
#define OFF_EBITS  65536u                // 2*2048*128 u16 = 1 MB
#define OFF_QBF    1114112u              // 4 MB bf16
#define OFF_KBF    5308416u              // 4 MB
#define OFF_VT     9502720u              // 4 MB (transposed [bh][d][n])
#define WS_NEEDED  13697024u

__device__ __forceinline__ unsigned short f2bf(float f) {
    unsigned u = __float_as_uint(f);
    return (unsigned short)((u + 0x7FFFu + ((u >> 16) & 1u)) >> 16);   // RNE
}

// ---- fused prepass: edge pack (blocks 0..2047), q/k/v convert (2048..2559),
//      mask pack+detect (2560..2575)
__global__ __launch_bounds__(256)
void prep_all(const float* __restrict__ q, const float* __restrict__ k,
              const float* __restrict__ v, const void* __restrict__ mraw,
              const int* __restrict__ edge,
              unsigned short* __restrict__ qbf, unsigned short* __restrict__ kbf,
              unsigned short* __restrict__ vT,
              unsigned short* __restrict__ e16, unsigned long long* __restrict__ mbits)
{
    __shared__ unsigned short shbuf[64][72];
    __shared__ int flag;
    const int bid = blockIdx.x;
    const int t   = threadIdx.x;

    if (bid < 2048) {               // ---- edge -> u16 bitmasks (thread-local)
        const int idx = bid * 256 + t;            // 0..524287
        const int4* p = (const int4*)(edge + (size_t)idx * 16);
        unsigned m = 0;
        #pragma unroll
        for (int i = 0; i < 4; ++i) {
            const int4 vv = p[i];
            m |= (vv.x != 0 ? 1u : 0u) << (i * 4 + 0);
            m |= (vv.y != 0 ? 1u : 0u) << (i * 4 + 1);
            m |= (vv.z != 0 ? 1u : 0u) << (i * 4 + 2);
            m |= (vv.w != 0 ? 1u : 0u) << (i * 4 + 3);
        }
        e16[idx] = (unsigned short)m;
    } else if (bid < 2560) {        // ---- q,k -> bf16; v -> bf16 transposed
        const int b2 = bid - 2048;
        const int rt = b2 & 31, bh = b2 >> 5;
        const size_t base = ((size_t)bh * N_ + (size_t)rt * 64) * D_;
        #pragma unroll
        for (int i = 0; i < 4; ++i) {
            const int idx = t + i * 256;
            float4 f = *(const float4*)(q + base + (size_t)idx * 4);
            ushort4 s; s.x = f2bf(f.x); s.y = f2bf(f.y); s.z = f2bf(f.z); s.w = f2bf(f.w);
            *(ushort4*)(qbf + base + (size_t)idx * 4) = s;
            f = *(const float4*)(k + base + (size_t)idx * 4);
            s.x = f2bf(f.x); s.y = f2bf(f.y); s.z = f2bf(f.z); s.w = f2bf(f.w);
            *(ushort4*)(kbf + base + (size_t)idx * 4) = s;
            f = *(const float4*)(v + base + (size_t)idx * 4);
            const int row = idx >> 4;
            const int d0  = (idx & 15) * 4;
            shbuf[d0 + 0][row] = f2bf(f.x);
            shbuf[d0 + 1][row] = f2bf(f.y);
            shbuf[d0 + 2][row] = f2bf(f.z);
            shbuf[d0 + 3][row] = f2bf(f.w);
        }
        __syncthreads();
        const int d  = t >> 2;
        const int c4 = (t & 3) * 16;
        const size_t ob = ((size_t)bh * D_ + d) * N_ + (size_t)rt * 64 + c4;
        *(us8*)(vT + ob)     = *(us8*)&shbuf[d][c4];
        *(us8*)(vT + ob + 8) = *(us8*)&shbuf[d][c4 + 8];
    } else {                        // ---- mask detect + pack
        const int bh = bid - 2560;
        if (t == 0) flag = 0;
        __syncthreads();
        const int* mi = (const int*)mraw;
        int bad = 0;
        for (int i = t; i < 8192; i += 256)
            if ((unsigned)mi[i] > 1u) bad = 1;
        if (bad) atomicOr(&flag, 1);
        __syncthreads();
        const int is_u8 = flag;
        const uint8_t* m8 = (const uint8_t*)mraw;
        const int w4 = t >> 6, l = t & 63;
        for (int it = 0; it < 8; ++it) {
            const int pos = bh * 2048 + it * 256 + w4 * 64 + l;
            const bool on = is_u8 ? (m8[pos] != 0) : (mi[pos] != 0);
            unsigned long long bal = __ballot(on);
            if (l == 0) mbits[bh * 32 + it * 4 + w4] = bal;
        }
    }
}

// ---- main v5: 64 query rows/block, 4 waves; wave w owns rows w*16..w*16+15.
// K (and V in pass 2) staged cooperatively ONCE per block (vs once per 16-row
// tile in v3/v4 -> 4x less LDS staging traffic), double-buffered, ONE barrier
// per chunk. P tile and row-sums are wave-private (row ownership) -> no sync.
__global__ __launch_bounds__(256)
void attn_v5(const unsigned short* __restrict__ qbf,
             const unsigned short* __restrict__ kbf,
             const unsigned short* __restrict__ vT,
             const unsigned long long* __restrict__ ebits,
             const unsigned long long* __restrict__ mbits,
             float* __restrict__ out, float* __restrict__ attn)
{
    __shared__ unsigned short sK[2][4096];   // 64 keys x 64 d bf16, swizzled 16B slots
    __shared__ unsigned short sV[2][4096];   // 64 d x 64 keys bf16, swizzled
    __shared__ char pbuf[4][2048];           // per-wave 16x64 bf16 P tile

    const int tile = blockIdx.x;    // 0..31
    const int bh   = blockIdx.y;
    const int t    = threadIdx.x;
    const int w    = t >> 6;
    const int lane = t & 63;
    const int l15  = lane & 15;
    const int lg   = lane >> 4;
    const int rbase = tile * 64;
    const int myrow = rbase + w * 16 + l15;   // this lane's P/attn row

    const unsigned short* qb = qbf + (size_t)bh * N_ * D_;
    const unsigned short* kb = kbf + (size_t)bh * N_ * D_;
    const unsigned short* vb = vT  + (size_t)bh * D_ * N_;
    const unsigned long long* ebrow =
        ebits + ((size_t)(bh & 1) * N_ + (size_t)myrow) * 32;
    const unsigned long long* mb = mbits + bh * 32;
    float* outb = out + (size_t)bh * N_ * D_;
    float* arow = attn + (size_t)bh * N_ * N_ + (size_t)myrow * N_ + lg * 4;

    // Q fragments (B-operand of swapped QK^T), row = myrow
    const bf16x8 aq0 = *(const bf16x8*)(qb + (size_t)myrow * D_ + lg * 8);
    const bf16x8 aq1 = *(const bf16x8*)(qb + (size_t)myrow * D_ + lg * 8 + 32);

    // cooperative staging: thread t covers 16B slots t and t+256 of each 8KB tile
    const int s0row = t >> 3;               // 0..31
    const int s1row = s0row + 32;           // 32..63
    const int t8    = t & 7;
    const int ds0 = s0row * 64 + ((t8 ^ (s0row & 7)) * 8);
    const int ds1 = s1row * 64 + ((t8 ^ (s1row & 7)) * 8);

    // =============== PASS 1: row sums of exp (K only) ===============
    {
        const us8 a0 = *(const us8*)(kb + (size_t)t * 8);
        const us8 a1 = *(const us8*)(kb + (size_t)(t + 256) * 8);
        *(us8*)(sK[0] + ds0) = a0;
        *(us8*)(sK[0] + ds1) = a1;
        __syncthreads();
    }
    float lacc = 0.f;
    #pragma unroll 1
    for (int kc = 0; kc < 32; ++kc) {
        const int cur = kc & 1;
        us8 nk0, nk1;
        if (kc < 31) {
            const unsigned short* s = kb + (size_t)(kc + 1) * 4096;
            nk0 = *(const us8*)(s + (size_t)t * 8);
            nk1 = *(const us8*)(s + (size_t)(t + 256) * 8);
        }
        const unsigned long long wbits = ebrow[kc] & ~mb[kc];
        const unsigned short* kcur = sK[cur];
        #pragma unroll
        for (int nt = 0; nt < 4; ++nt) {
            const int row = nt * 16 + l15, sw = row & 7;
            const bf16x8 k0 = *(const bf16x8*)(kcur + row * 64 + ((lg ^ sw) * 8));
            const bf16x8 k1 = *(const bf16x8*)(kcur + row * 64 + (((lg + 4) ^ sw) * 8));
            f32x4 c = (f32x4){0.f, 0.f, 0.f, 0.f};
            c = __builtin_amdgcn_mfma_f32_16x16x32_bf16(k0, aq0, c, 0, 0, 0);
            c = __builtin_amdgcn_mfma_f32_16x16x32_bf16(k1, aq1, c, 0, 0, 0);
            const unsigned bits = (unsigned)(wbits >> (nt * 16 + lg * 4)) & 0xFu;
            #pragma unroll
            for (int r = 0; r < 4; ++r)
                lacc += ((bits >> r) & 1u) ? __expf(c[r] * 0.125f) : 0.f;
        }
        if (kc < 31) {   // write next chunk into the other buffer (its last
                         // readers finished at the kc-1 barrier)
            *(us8*)(sK[cur ^ 1] + ds0) = nk0;
            *(us8*)(sK[cur ^ 1] + ds1) = nk1;
        }
        __syncthreads();
    }
    lacc += __shfl_xor(lacc, 16);
    lacc += __shfl_xor(lacc, 32);
    const float inv = 1.0f / lacc;     // full row sum (row l15 of wave w's tile)

    // =============== PASS 2: recompute, store attn, PV ===============
    {   // prologue: stage K[0], V[0]  (pass-1 loop ended with a barrier)
        const us8 a0 = *(const us8*)(kb + (size_t)t * 8);
        const us8 a1 = *(const us8*)(kb + (size_t)(t + 256) * 8);
        const us8 b0 = *(const us8*)(vb + (size_t)s0row * 2048 + t8 * 8);
        const us8 b1 = *(const us8*)(vb + (size_t)s1row * 2048 + t8 * 8);
        *(us8*)(sK[0] + ds0) = a0;
        *(us8*)(sK[0] + ds1) = a1;
        *(us8*)(sV[0] + ds0) = b0;
        *(us8*)(sV[0] + ds1) = b1;
        __syncthreads();
    }

    f32x4 o[4];
    #pragma unroll
    for (int nt = 0; nt < 4; ++nt) o[nt] = (f32x4){0.f, 0.f, 0.f, 0.f};

    char* pbw = pbuf[w];
    const int swzP = (l15 & 7) << 4;
    const int ab0 = (l15 * 128 + lg * 16)      ^ swzP;
    const int ab1 = (l15 * 128 + lg * 16 + 64) ^ swzP;

    #pragma unroll 1
    for (int kc = 0; kc < 32; ++kc) {
        const int cur = kc & 1;
        us8 nk0, nk1, nv0, nv1;
        if (kc < 31) {
            const unsigned short* srck = kb + (size_t)(kc + 1) * 4096;
            const unsigned short* srcv = vb + (size_t)(kc + 1) * 64;
            nk0 = *(const us8*)(srck + (size_t)t * 8);
            nk1 = *(const us8*)(srck + (size_t)(t + 256) * 8);
            nv0 = *(const us8*)(srcv + (size_t)s0row * 2048 + t8 * 8);
            nv1 = *(const us8*)(srcv + (size_t)s1row * 2048 + t8 * 8);
        }
        const unsigned long long wbits = ebrow[kc] & ~mb[kc];
        const unsigned short* kcur = sK[cur];
        float* astore = arow + kc * 64;
        #pragma unroll
        for (int nt = 0; nt < 4; ++nt) {
            const int row = nt * 16 + l15, sw = row & 7;
            const bf16x8 k0 = *(const bf16x8*)(kcur + row * 64 + ((lg ^ sw) * 8));
            const bf16x8 k1 = *(const bf16x8*)(kcur + row * 64 + (((lg + 4) ^ sw) * 8));
            f32x4 c = (f32x4){0.f, 0.f, 0.f, 0.f};
            c = __builtin_amdgcn_mfma_f32_16x16x32_bf16(k0, aq0, c, 0, 0, 0);
            c = __builtin_amdgcn_mfma_f32_16x16x32_bf16(k1, aq1, c, 0, 0, 0);
            const unsigned bits = (unsigned)(wbits >> (nt * 16 + lg * 4)) & 0xFu;
            float4 e;
            e.x = (bits & 1u) ? __expf(c[0] * 0.125f) * inv : 0.f;
            e.y = (bits & 2u) ? __expf(c[1] * 0.125f) * inv : 0.f;
            e.z = (bits & 4u) ? __expf(c[2] * 0.125f) * inv : 0.f;
            e.w = (bits & 8u) ? __expf(c[3] * 0.125f) * inv : 0.f;
            *(float4*)(astore + nt * 16) = e;          // 4 contiguous keys, row myrow
            ushort4 pe;
            pe.x = f2bf(e.x); pe.y = f2bf(e.y); pe.z = f2bf(e.z); pe.w = f2bf(e.w);
            const int wbyte = (l15 * 128 + nt * 32 + lg * 8) ^ swzP;  // XOR last
            *(ushort4*)(pbw + wbyte) = pe;             // wave-private P tile
        }
        // PV: own P rows x all d (per-wave in-order DS, no barrier needed)
        const bf16x8 ap0 = *(const bf16x8*)(pbw + ab0);
        const bf16x8 ap1 = *(const bf16x8*)(pbw + ab1);
        const unsigned short* vcur = sV[cur];
        #pragma unroll
        for (int nt = 0; nt < 4; ++nt) {
            const int row = nt * 16 + l15, sw = row & 7;   // d-row
            const bf16x8 bv0 = *(const bf16x8*)(vcur + row * 64 + ((lg ^ sw) * 8));
            const bf16x8 bv1 = *(const bf16x8*)(vcur + row * 64 + (((lg + 4) ^ sw) * 8));
            o[nt] = __builtin_amdgcn_mfma_f32_16x16x32_bf16(ap0, bv0, o[nt], 0, 0, 0);
            o[nt] = __builtin_amdgcn_mfma_f32_16x16x32_bf16(ap1, bv1, o[nt], 0, 0, 0);
        }
        if (kc < 31) {
            *(us8*)(sK[cur ^ 1] + ds0) = nk0;
            *(us8*)(sK[cur ^ 1] + ds1) = nk1;
            *(us8*)(sV[cur ^ 1] + ds0) = nv0;
            *(us8*)(sV[cur ^ 1] + ds1) = nv1;
        }
        __syncthreads();
    }

    // epilogue: wave w owns rows w*16..w*16+15 completely
    #pragma unroll
    for (int nt = 0; nt < 4; ++nt)
        #pragma unroll
        for (int r = 0; r < 4; ++r)
            outb[(size_t)(rbase + w * 16 + lg * 4 + r) * D_ + nt * 16 + l15] = o[nt][r];
}

// ================= fallback (fp32 path, needs only 32 KB ws) =================
__global__ __launch_bounds__(256)
void normalize_mask(const void* __restrict__ mask_raw, uint8_t* __restrict__ mask_out)
{
    __shared__ int is_u8;
    const int t = threadIdx.x;
    if (t == 0) is_u8 = 0;
    __syncthreads();
    const int* mi = (const int*)mask_raw;
    int bad = 0;
    for (int i = t; i < 8192; i += 256)
        if ((unsigned)mi[i] > 1u) bad = 1;
    if (bad) atomicOr(&is_u8, 1);
    __syncthreads();
    const int total = BH_ * N_;
    if (is_u8) {
        const uint8_t* m8 = (const uint8_t*)mask_raw;
        for (int i = t; i < total; i += 256) mask_out[i] = m8[i] ? 1 : 0;
    } else {
        for (int i = t; i < total; i += 256) mask_out[i] = (uint8_t)mi[i];
    }
}

__global__ __launch_bounds__(256)
void attn_fused(const float* __restrict__ q, const float* __restrict__ k,
                const float* __restrict__ v, const uint8_t* __restrict__ mask,
                const int* __restrict__ edge, float* __restrict__ out,
                float* __restrict__ attn)
{
    __shared__ float qsT[D_][64 + 4];
    __shared__ float kt [D_][64 + 4];
    __shared__ float vs [64][D_ + 4];
    const int tile = blockIdx.x, bh = blockIdx.y, t = threadIdx.x;
    const int rg = t >> 4, cg = t & 15, r0 = rg * 4, c0 = cg * 4;
    const int row_base = tile * 64;
    const float* qb = q + (size_t)bh * N_ * D_;
    const float* kb = k + (size_t)bh * N_ * D_;
    const float* vb = v + (size_t)bh * N_ * D_;
    const uint8_t* mbp = mask + (size_t)bh * N_;
    const int* ebp = edge + (size_t)(bh & 1) * N_ * N_;
    float* outb = out + (size_t)bh * N_ * D_;
    float* attnb = attn + (size_t)bh * N_ * N_;
    {
        const int rr = t >> 2, dblk = (t & 3) * 16;
        const float* src = qb + (size_t)(row_base + rr) * D_ + dblk;
        #pragma unroll
        for (int qq = 0; qq < 4; ++qq) {
            float4 val = *(const float4*)(src + qq * 4);
            qsT[dblk + qq*4 + 0][rr] = val.x; qsT[dblk + qq*4 + 1][rr] = val.y;
            qsT[dblk + qq*4 + 2][rr] = val.z; qsT[dblk + qq*4 + 3][rr] = val.w;
        }
    }
    float m_i[4], l_i[4];
    #pragma unroll
    for (int i = 0; i < 4; ++i) { m_i[i] = -INFINITY; l_i[i] = 0.f; }
    for (int kc = 0; kc < 32; ++kc) {
        __syncthreads();
        {
            const int ccr = t >> 2, dblk = (t & 3) * 16;
            const float* src = kb + (size_t)(kc * 64 + ccr) * D_ + dblk;
            #pragma unroll
            for (int qq = 0; qq < 4; ++qq) {
                float4 val = *(const float4*)(src + qq * 4);
                kt[dblk + qq*4 + 0][ccr] = val.x; kt[dblk + qq*4 + 1][ccr] = val.y;
                kt[dblk + qq*4 + 2][ccr] = val.z; kt[dblk + qq*4 + 3][ccr] = val.w;
            }
        }
        __syncthreads();
        float sc[4][4];
        #pragma unroll
        for (int i = 0; i < 4; ++i) { sc[i][0]=sc[i][1]=sc[i][2]=sc[i][3]=0.f; }
        for (int d = 0; d < D_; ++d) {
            const float4 qv = *(const float4*)&qsT[d][r0];
            const float4 kv = *(const float4*)&kt[d][c0];
            #pragma unroll
            for (int i = 0; i < 4; ++i) {
                const float qi = (i==0)?qv.x:(i==1)?qv.y:(i==2)?qv.z:qv.w;
                sc[i][0] = fmaf(qi, kv.x, sc[i][0]); sc[i][1] = fmaf(qi, kv.y, sc[i][1]);
                sc[i][2] = fmaf(qi, kv.z, sc[i][2]); sc[i][3] = fmaf(qi, kv.w, sc[i][3]);
            }
        }
        const int cbase = kc * 64 + c0;
        const uint8_t m0 = mbp[cbase], m1 = mbp[cbase+1], m2 = mbp[cbase+2], m3 = mbp[cbase+3];
        #pragma unroll
        for (int i = 0; i < 4; ++i) {
            const int rglob = row_base + r0 + i;
            const int4 e4 = *(const int4*)(ebp + (size_t)rglob * N_ + cbase);
            float s0 = sc[i][0]*0.125f, s1 = sc[i][1]*0.125f, s2 = sc[i][2]*0.125f, s3 = sc[i][3]*0.125f;
            if (e4.x == 0 || m0) s0 = NEGV; if (e4.y == 0 || m1) s1 = NEGV;
            if (e4.z == 0 || m2) s2 = NEGV; if (e4.w == 0 || m3) s3 = NEGV;
            float cmax = fmaxf(fmaxf(s0,s1), fmaxf(s2,s3));
            cmax = fmaxf(cmax, __shfl_xor(cmax,1)); cmax = fmaxf(cmax, __shfl_xor(cmax,2));
            cmax = fmaxf(cmax, __shfl_xor(cmax,4)); cmax = fmaxf(cmax, __shfl_xor(cmax,8));
            const float nm = fmaxf(m_i[i], cmax);
            float ss = __expf(s0-nm)+__expf(s1-nm)+__expf(s2-nm)+__expf(s3-nm);
            ss += __shfl_xor(ss,1); ss += __shfl_xor(ss,2); ss += __shfl_xor(ss,4); ss += __shfl_xor(ss,8);
            l_i[i] = l_i[i]*__expf(m_i[i]-nm) + ss; m_i[i] = nm;
        }
    }
    float inv_l[4];
    #pragma unroll
    for (int i = 0; i < 4; ++i) inv_l[i] = 1.0f / l_i[i];
    float oacc[4][4];
    #pragma unroll
    for (int i = 0; i < 4; ++i) { oacc[i][0]=oacc[i][1]=oacc[i][2]=oacc[i][3]=0.f; }
    for (int kc = 0; kc < 32; ++kc) {
        __syncthreads();
        {
            const int ccr = t >> 2, dblk = (t & 3) * 16;
            const float* src = kb + (size_t)(kc * 64 + ccr) * D_ + dblk;
            #pragma unroll
            for (int qq = 0; qq < 4; ++qq) {
                float4 val = *(const float4*)(src + qq * 4);
                kt[dblk + qq*4 + 0][ccr] = val.x; kt[dblk + qq*4 + 1][ccr] = val.y;
                kt[dblk + qq*4 + 2][ccr] = val.z; kt[dblk + qq*4 + 3][ccr] = val.w;
            }
            const float* srcv = vb + (size_t)(kc * 64 + ccr) * D_ + dblk;
            #pragma unroll
            for (int qq = 0; qq < 4; ++qq)
                *(float4*)&vs[ccr][dblk + qq * 4] = *(const float4*)(srcv + qq * 4);
        }
        __syncthreads();
        float sc[4][4];
        #pragma unroll
        for (int i = 0; i < 4; ++i) { sc[i][0]=sc[i][1]=sc[i][2]=sc[i][3]=0.f; }
        for (int d = 0; d < D_; ++d) {
            const float4 qv = *(const float4*)&qsT[d][r0];
            const float4 kv = *(const float4*)&kt[d][c0];
            #pragma unroll
            for (int i = 0; i < 4; ++i) {
                const float qi = (i==0)?qv.x:(i==1)?qv.y:(i==2)?qv.z:qv.w;
                sc[i][0] = fmaf(qi, kv.x, sc[i][0]); sc[i][1] = fmaf(qi, kv.y, sc[i][1]);
                sc[i][2] = fmaf(qi, kv.z, sc[i][2]); sc[i][3] = fmaf(qi, kv.w, sc[i][3]);
            }
        }
        const int cbase = kc * 64 + c0;
        const uint8_t m0 = mbp[cbase], m1 = mbp[cbase+1], m2 = mbp[cbase+2], m3 = mbp[cbase+3];
        float p[4][4];
        #pragma unroll
        for (int i = 0; i < 4; ++i) {
            const int rglob = row_base + r0 + i;
            const int4 e4 = *(const int4*)(ebp + (size_t)rglob * N_ + cbase);
            float s0 = sc[i][0]*0.125f, s1 = sc[i][1]*0.125f, s2 = sc[i][2]*0.125f, s3 = sc[i][3]*0.125f;
            if (e4.x == 0 || m0) s0 = NEGV; if (e4.y == 0 || m1) s1 = NEGV;
            if (e4.z == 0 || m2) s2 = NEGV; if (e4.w == 0 || m3) s3 = NEGV;
            p[i][0] = __expf(s0-m_i[i])*inv_l[i]; p[i][1] = __expf(s1-m_i[i])*inv_l[i];
            p[i][2] = __expf(s2-m_i[i])*inv_l[i]; p[i][3] = __expf(s3-m_i[i])*inv_l[i];
            *(float4*)&attnb[(size_t)rglob * N_ + cbase] = make_float4(p[i][0],p[i][1],p[i][2],p[i][3]);
        }
        __syncthreads();
        #pragma unroll
        for (int i = 0; i < 4; ++i)
            *(float4*)&kt[r0 + i][c0] = make_float4(p[i][0],p[i][1],p[i][2],p[i][3]);
        __syncthreads();
        for (int c4 = 0; c4 < 64; c4 += 4) {
            float prr[4][4];
            #pragma unroll
            for (int i = 0; i < 4; ++i) {
                const float4 tmp = *(const float4*)&kt[r0 + i][c4];
                prr[i][0]=tmp.x; prr[i][1]=tmp.y; prr[i][2]=tmp.z; prr[i][3]=tmp.w;
            }
            #pragma unroll
            for (int cc = 0; cc < 4; ++cc) {
                const float4 vv = *(const float4*)&vs[c4 + cc][c0];
                #pragma unroll
                for (int i = 0; i < 4; ++i) {
                    oacc[i][0] = fmaf(prr[i][cc], vv.x, oacc[i][0]);
                    oacc[i][1] = fmaf(prr[i][cc], vv.y, oacc[i][1]);
                    oacc[i][2] = fmaf(prr[i][cc], vv.z, oacc[i][2]);
                    oacc[i][3] = fmaf(prr[i][cc], vv.w, oacc[i][3]);
                }
            }
        }
    }
    #pragma unroll
    for (int i = 0; i < 4; ++i)
        *(float4*)&outb[(size_t)(row_base + r0 + i) * D_ + c0] =
            make_float4(oacc[i][0], oacc[i][1], oacc[i][2], oacc[i][3]);
}

extern "C" void kernel_launch(void* const* d_in, const int* in_sizes, int n_in,
                              void* d_out, int out_size, void* d_ws, size_t ws_size,
                              hipStream_t stream) {
    const float* q    = (const float*)d_in[0];
    const float* k    = (const float*)d_in[1];
    const float* v    = (const float*)d_in[2];
    // d_in[3] = k2 (unused by the reference)
    const void*  mraw = d_in[4];
    const int*   edge = (const int*)d_in[5];

    float* out  = (float*)d_out;                         // [16][2048][64]
    float* attn = (float*)d_out + (size_t)BH_ * N_ * D_; // [16][2048][2048]

    char* ws = (char*)d_ws;

    if (ws_size < (size_t)WS_NEEDED) {
        uint8_t* mask_u8 = (uint8_t*)(ws + OFF_MASKU8);
        normalize_mask<<<1, 256, 0, stream>>>(mraw, mask_u8);
        attn_fused<<<dim3(32, 16), 256, 0, stream>>>(q, k, v, mask_u8, edge, out, attn);
        return;
    }

    unsigned long long* mbits = (unsigned long long*)(ws + OFF_MBITS);
    unsigned short*     e16   = (unsigned short*)(ws + OFF_EBITS);
    unsigned short*     qbf   = (unsigned short*)(ws + OFF_QBF);
    unsigned short*     kbf   = (unsigned short*)(ws + OFF_KBF);
    unsigned short*     vT    = (unsigned short*)(ws + OFF_VT);

    prep_all<<<dim3(2576), 256, 0, stream>>>(q, k, v, mraw, edge,
                                             qbf, kbf, vT, e16, mbits);
    attn_v5<<<dim3(N_ / 64, BH_), 256, 0, stream>>>(
        qbf, kbf, vT, (const unsigned long long*)e16, mbits, out, attn);
}